// Round 1
// baseline (383.570 us; speedup 1.0000x reference)
//
#include <hip/hip_runtime.h>

// Downsample1d: depthwise stride-2 FIR, taps [1/8, 3/8, 3/8, 1/8], reflect pad 1.
// x: [B=8, C=128, T=65536] fp32  ->  out: [8, 128, 32768] fp32
// out[t] = 0.125*(x[2t-1] + x[2t+2]) + 0.375*(x[2t] + x[2t+1])
// reflect: x[-1] -> x[1], x[T] -> x[T-2]

#define T_LEN   65536
#define TO_LEN  32768
#define ROWS    1024            // B*C
#define JPR     (TO_LEN / 4)    // threads per row, 4 outputs each = 8192

__global__ __launch_bounds__(256)
void ds1d_kernel(const float* __restrict__ x, float* __restrict__ out) {
    int g   = blockIdx.x * 256 + threadIdx.x;
    int row = g >> 13;            // g / JPR
    int j   = g & (JPR - 1);
    long long xbase = (long long)row * T_LEN;
    long long obase = (long long)row * TO_LEN;
    int i0 = j << 3;              // input start index for this thread's 4 outputs

    // two aligned 16B loads: x[i0..i0+3], x[i0+4..i0+7]
    const float4* xv = (const float4*)(x + xbase + i0);
    float4 a = xv[0];
    float4 b = xv[1];

    // boundary neighbors, branchless reflect (L1 hits except at row edges)
    int im1 = (i0 == 0)            ? 1           : (i0 - 1);
    int ip8 = (i0 + 8 >= T_LEN)    ? (T_LEN - 2) : (i0 + 8);
    float xm1 = x[xbase + im1];
    float xp8 = x[xbase + ip8];

    float4 y;
    y.x = 0.125f * (xm1 + a.z) + 0.375f * (a.x + a.y);
    y.y = 0.125f * (a.y + b.x) + 0.375f * (a.z + a.w);
    y.z = 0.125f * (a.w + b.z) + 0.375f * (b.x + b.y);
    y.w = 0.125f * (b.y + xp8) + 0.375f * (b.z + b.w);

    *(float4*)(out + obase + (j << 2)) = y;
}

extern "C" void kernel_launch(void* const* d_in, const int* in_sizes, int n_in,
                              void* d_out, int out_size, void* d_ws, size_t ws_size,
                              hipStream_t stream) {
    const float* x = (const float*)d_in[0];
    // d_in[1] is the fixed FIR taps [1/8,3/8,3/8,1/8]; hardcoded above.
    float* out = (float*)d_out;

    int total_threads = ROWS * JPR;          // 8,388,608
    int blocks = total_threads / 256;        // 32,768
    ds1d_kernel<<<blocks, 256, 0, stream>>>(x, out);
}